// Round 10
// baseline (168.767 us; speedup 1.0000x reference)
//
#include <hip/hip_runtime.h>

#define NN 50000
#define NE 800000
#define KIN 512
#define HC 128
#define SCAN_NB ((NN + 255) / 256)   // 196

typedef float f32x4 __attribute__((ext_vector_type(4)));
typedef float f32x2 __attribute__((ext_vector_type(2)));
typedef short s16x8 __attribute__((ext_vector_type(8)));

__device__ __forceinline__ ushort f2bf(float f) {
  unsigned u = __float_as_uint(f);
  unsigned r = (u + 0x7FFFu + ((u >> 16) & 1u)) >> 16;  // RNE
  return (ushort)r;
}

// async global->LDS, 16B per lane, dest = wave-uniform base + lane*16
__device__ __forceinline__ void gload_lds16(const void* g, void* l) {
  __builtin_amdgcn_global_load_lds((const __attribute__((address_space(1))) void*)g,
                                   (__attribute__((address_space(3))) void*)l, 16, 0, 0);
}

// JAX threefry2x32-20, partitionable path: ctr=(0,i), key=(0,42), bits=o0^o1
__device__ __forceinline__ unsigned tf_bits(unsigned i) {
  unsigned x0 = 0u, x1 = i;
  const unsigned ks0 = 0u, ks1 = 42u, ks2 = 0x1BD11BDAu ^ 42u;
  x0 += ks0; x1 += ks1;
#define R(r) { x0 += x1; x1 = (x1 << r) | (x1 >> (32 - r)); x1 ^= x0; }
  R(13) R(15) R(26) R(6)
  x0 += ks1; x1 += ks2 + 1u;
  R(17) R(29) R(16) R(24)
  x0 += ks2; x1 += ks0 + 2u;
  R(13) R(15) R(26) R(6)
  x0 += ks0; x1 += ks1 + 3u;
  R(17) R(29) R(16) R(24)
  x0 += ks1; x1 += ks2 + 4u;
  R(13) R(15) R(26) R(6)
  x0 += ks2; x1 += ks0 + 5u;
#undef R
  return x0 ^ x1;
}

__global__ void k_zero(int* __restrict__ cnt) {
  int i = blockIdx.x * 256 + threadIdx.x;
  if (i < NN) cnt[i] = 0;
}

// count dst degrees (cnt zeroed by k_zero) + W transpose/convert
__global__ void k_cntprep(const int* __restrict__ ei, int* __restrict__ cnt,
                          const float* __restrict__ W, ushort* __restrict__ Wt) {
  int t = blockIdx.x * 256 + threadIdx.x;
  if (t < KIN * HC) {
    int c = t & (HC - 1), k = t >> 7;       // W row-major [k][c]
    Wt[c * KIN + k] = f2bf(W[t]);
  }
  if (t < NE) atomicAdd(&cnt[ei[NE + t]], 1);
}

// per-block exclusive scan of cnt; off = block-local exclusive, bsum[b] = total
__global__ void k_scan1(const int* __restrict__ cnt, int* __restrict__ off,
                        float* __restrict__ dinv, int* __restrict__ bsum) {
  const int i = blockIdx.x * 256 + threadIdx.x;
  const int lane = threadIdx.x & 63, wid = threadIdx.x >> 6;
  int c = (i < NN) ? cnt[i] : 0;
  if (i < NN) dinv[i] = rsqrtf((float)(c + 1));
  int v = c;
#pragma unroll
  for (int d = 1; d < 64; d <<= 1) {
    int t = __shfl_up(v, d);
    if (lane >= d) v += t;
  }
  __shared__ int wsum[4];
  if (lane == 63) wsum[wid] = v;
  __syncthreads();
  int wadd = 0;
#pragma unroll
  for (int w = 0; w < 3; w++) if (w < wid) wadd += wsum[w];
  int incl = v + wadd;
  if (i < NN) off[i] = incl - c;            // block-local exclusive
  if (threadIdx.x == 255) bsum[blockIdx.x] = incl;
}

// exclusive scan of SCAN_NB (<=256) block sums, in place; also off[NN]=NE
__global__ void k_scan2(int* __restrict__ bsum, int* __restrict__ off) {
  const int t = threadIdx.x;
  const int lane = t & 63, wid = t >> 6;
  int c = (t < SCAN_NB) ? bsum[t] : 0;
  int v = c;
#pragma unroll
  for (int d = 1; d < 64; d <<= 1) {
    int u = __shfl_up(v, d);
    if (lane >= d) v += u;
  }
  __shared__ int wsum[4];
  if (lane == 63) wsum[wid] = v;
  __syncthreads();
  int wadd = 0;
#pragma unroll
  for (int w = 0; w < 3; w++) if (w < wid) wadd += wsum[w];
  if (t < SCAN_NB) bsum[t] = v + wadd - c;  // exclusive
  if (t == 0) off[NN] = NE;
}

// csrp[off[d]+bsum[d>>8]+slot] = (bf16(dinv[src])<<16) | src   (src < 65536)
__global__ void k_fill(const int* __restrict__ ei, const int* __restrict__ off,
                       const int* __restrict__ bsum, int* __restrict__ cnt,
                       const float* __restrict__ dinv, unsigned* __restrict__ csrp) {
  int e = blockIdx.x * 256 + threadIdx.x;
  if (e >= NE) return;
  int s = ei[e], d = ei[NE + e];
  int slot = atomicAdd(&cnt[d], -1) - 1;    // cnt ends back at 0
  csrp[off[d] + bsum[d >> 8] + slot] = ((unsigned)f2bf(dinv[s]) << 16) | (unsigned)s;
}

// x = feats @ W  (bf16 MFMA, f32 acc, bf16 out). 64x128 tile, 4 waves 2x2.
// A double-buffered in LDS via global_load_lds (XOR-chunk swizzle, pre-swizzled
// source); B frags direct from L2-resident Wt. ONE barrier per K-step: stage
// of step t+1 is issued before step t's compute and flies under it.
__launch_bounds__(256, 3)
__global__ void k_gemm(const float* __restrict__ feats, const ushort* __restrict__ Wt,
                       ushort* __restrict__ xb) {
  __shared__ __align__(16) float As[2][64 * 64];  // 2 x 16 KB, 256 B/row
  const int tid = threadIdx.x;
  const int lane = tid & 63;
  const int w = tid >> 6;
  const int wm = w >> 1, wn = w & 1;
  const int rbase = blockIdx.x * 64;              // 782 blocks

  f32x4 acc[2][4];
#pragma unroll
  for (int mt = 0; mt < 2; mt++)
#pragma unroll
    for (int nt = 0; nt < 4; nt++) acc[mt][nt] = f32x4{0.f, 0.f, 0.f, 0.f};

  // A staging geometry: wave w stages rows w*16+i*4+(lane>>4), i=0..3
  const int a_rt = w * 16 + (lane >> 4);
  int a_gr[4];
#pragma unroll
  for (int i = 0; i < 4; i++) {
    int gr = rbase + a_rt + i * 4;
    a_gr[i] = (gr < NN) ? gr : NN - 1;
  }
  // B column pointers (direct global, L2-hot): col = wn*64+nt*16+(lane&15)
  const ushort* bcol[4];
#pragma unroll
  for (int nt = 0; nt < 4; nt++)
    bcol[nt] = Wt + (size_t)(wn * 64 + nt * 16 + (lane & 15)) * KIN + (lane >> 4) * 8;

#define STAGE_A(KS, BUF)                                                       \
  _Pragma("unroll")                                                            \
  for (int i = 0; i < 4; i++) {                                                \
    int a_ch = ((lane & 15) ^ (a_rt & 7) ^ ((i & 1) << 2)) << 2;               \
    gload_lds16(feats + (size_t)a_gr[i] * KIN + (KS) + a_ch,                   \
                (char*)(BUF) + (w * 16 + i * 4) * 256);                        \
  }

  STAGE_A(0, As[0]);                              // prologue
  int cur = 0;
  for (int ks = 0; ks < KIN; ks += 64, cur ^= 1) {
    __syncthreads();                              // As[cur] staged & prev reads done
    if (ks + 64 < KIN) { STAGE_A(ks + 64, As[cur ^ 1]); }
    const char* Ab = (const char*)As[cur];
#pragma unroll
    for (int kk = 0; kk < 2; kk++) {
      s16x8 bfr[4];
#pragma unroll
      for (int nt = 0; nt < 4; nt++)
        bfr[nt] = *(const s16x8*)(bcol[nt] + ks + kk * 32);
#pragma unroll
      for (int mt = 0; mt < 2; mt++) {
        int r = wm * 32 + mt * 16 + (lane & 15);
        int c0 = kk * 8 + (lane >> 4) * 2;
        f32x4 f0 = *(const f32x4*)(Ab + r * 256 + ((c0 ^ (r & 7)) * 16));
        f32x4 f1 = *(const f32x4*)(Ab + r * 256 + (((c0 + 1) ^ (r & 7)) * 16));
        s16x8 af;
#pragma unroll
        for (int t = 0; t < 4; t++) {
          af[t]     = (short)f2bf(f0[t]);
          af[t + 4] = (short)f2bf(f1[t]);
        }
#pragma unroll
        for (int nt = 0; nt < 4; nt++)
          acc[mt][nt] = __builtin_amdgcn_mfma_f32_16x16x32_bf16(af, bfr[nt], acc[mt][nt], 0, 0, 0);
      }
    }
  }
#undef STAGE_A
  // C/D frag: col = lane&15, row = (lane>>4)*4 + j
#pragma unroll
  for (int mt = 0; mt < 2; mt++) {
    int rb = rbase + wm * 32 + mt * 16 + (lane >> 4) * 4;
#pragma unroll
    for (int nt = 0; nt < 4; nt++) {
      int c = wn * 64 + nt * 16 + (lane & 15);
#pragma unroll
      for (int j = 0; j < 4; j++) {
        int r = rb + j;
        if (r < NN) xb[(size_t)r * HC + c] = f2bf(acc[mt][nt][j]);
      }
    }
  }
}

// one wave per node, 4-way edge split: 16-lane group grp handles edges 4j+grp;
// each lane covers 8 channels (16B gather). Two shfl_xor levels to reduce.
__global__ void k_agg(const ushort* __restrict__ xb, const float* __restrict__ dinv,
                      const int* __restrict__ off, const int* __restrict__ bsum,
                      const unsigned* __restrict__ csrp,
                      const float* __restrict__ b, float* __restrict__ out) {
  int n = blockIdx.x * 4 + (threadIdx.x >> 6);
  if (n >= NN) return;
  const int lane = threadIdx.x & 63;
  const int grp = lane >> 4;          // edge slot parity (0..3)
  const int q = lane & 15;            // channels q*8 .. q*8+7
  const int beg = off[n] + bsum[n >> 8];
  const int end = off[n + 1] + ((n + 1 < NN) ? bsum[(n + 1) >> 8] : 0);
  const int deg = end - beg;
  const float dn = dinv[n];

  float a0, a1, a2, a3, a4, a5, a6, a7;
  {
    uint4 sv = *(const uint4*)(xb + (size_t)n * HC + q * 8);
    f32x4 b0 = *(const f32x4*)(b + q * 8);
    f32x4 b1 = *(const f32x4*)(b + q * 8 + 4);
    float sc = (grp == 0) ? dn * dn : 0.0f;   // self+bias only in group 0
    float z = (grp == 0) ? 1.0f : 0.0f;
    a0 = __uint_as_float(sv.x << 16)         * sc + b0[0] * z;
    a1 = __uint_as_float(sv.x & 0xFFFF0000u) * sc + b0[1] * z;
    a2 = __uint_as_float(sv.y << 16)         * sc + b0[2] * z;
    a3 = __uint_as_float(sv.y & 0xFFFF0000u) * sc + b0[3] * z;
    a4 = __uint_as_float(sv.z << 16)         * sc + b1[0] * z;
    a5 = __uint_as_float(sv.z & 0xFFFF0000u) * sc + b1[1] * z;
    a6 = __uint_as_float(sv.w << 16)         * sc + b1[2] * z;
    a7 = __uint_as_float(sv.w & 0xFFFF0000u) * sc + b1[3] * z;
  }

  const unsigned* cp = csrp + beg;
  const int np = (deg + 3) >> 2;      // quads
  unsigned uc = 0u;
  if (grp < deg) uc = cp[grp];        // edge 0*4+grp
  uint4 g = *(const uint4*)(xb + (size_t)(uc & 0xFFFFu) * HC + q * 8);
  for (int j = 0; j < np; ++j) {
    int idx = 4 * j + 4 + grp;        // next quad's edge for this group
    unsigned ucn = 0u;
    if (idx < deg) ucn = cp[idx];
    uint4 gn = *(const uint4*)(xb + (size_t)(ucn & 0xFFFFu) * HC + q * 8);
    float nr = __uint_as_float(uc & 0xFFFF0000u) * dn;  // bf16(dinv[src])*dinv[n]
    a0 += __uint_as_float(g.x << 16)         * nr;
    a1 += __uint_as_float(g.x & 0xFFFF0000u) * nr;
    a2 += __uint_as_float(g.y << 16)         * nr;
    a3 += __uint_as_float(g.y & 0xFFFF0000u) * nr;
    a4 += __uint_as_float(g.z << 16)         * nr;
    a5 += __uint_as_float(g.z & 0xFFFF0000u) * nr;
    a6 += __uint_as_float(g.w << 16)         * nr;
    a7 += __uint_as_float(g.w & 0xFFFF0000u) * nr;
    uc = ucn; g = gn;
  }
  // reduce across the 4 groups
#define RED(A) A += __shfl_xor(A, 16); A += __shfl_xor(A, 32);
  RED(a0) RED(a1) RED(a2) RED(a3) RED(a4) RED(a5) RED(a6) RED(a7)
#undef RED
  // group grp finalizes channels q*8+2*grp, q*8+2*grp+1
  float vx = (grp == 0) ? a0 : (grp == 1) ? a2 : (grp == 2) ? a4 : a6;
  float vy = (grp == 0) ? a1 : (grp == 1) ? a3 : (grp == 2) ? a5 : a7;
  vx = fmaxf(vx, 0.f) * 2.f;
  vy = fmaxf(vy, 0.f) * 2.f;
  int i0 = n * HC + q * 8 + 2 * grp;
  f32x2 r;
  r.x = (tf_bits((unsigned)i0)     >> 31) ? 0.f : vx;
  r.y = (tf_bits((unsigned)i0 + 1) >> 31) ? 0.f : vy;
  *(f32x2*)(out + i0) = r;
}

extern "C" void kernel_launch(void* const* d_in, const int* in_sizes, int n_in,
                              void* d_out, int out_size, void* d_ws, size_t ws_size,
                              hipStream_t stream) {
  const float* feats = (const float*)d_in[0];
  const float* W     = (const float*)d_in[1];
  const float* b     = (const float*)d_in[2];
  const int*   ei    = (const int*)d_in[3];
  float* out = (float*)d_out;

  // ws: xb[NN*HC] bf16 | Wt[HC*KIN] bf16 | dinv[NN] f32 | cnt[NN] i32 |
  //     off[NN+1] i32 | bsum[256] i32 | csrp[NE] u32   (~17 MB)
  char* ws = (char*)d_ws;
  size_t o = 0;
  ushort*   xb   = (ushort*)(ws + o);   o += ((size_t)NN * HC * 2 + 255) & ~(size_t)255;
  ushort*   Wt   = (ushort*)(ws + o);   o += ((size_t)HC * KIN * 2 + 255) & ~(size_t)255;
  float*    dinv = (float*)(ws + o);    o += ((size_t)NN * 4 + 255) & ~(size_t)255;
  int*      cnt  = (int*)(ws + o);      o += ((size_t)NN * 4 + 255) & ~(size_t)255;
  int*      off  = (int*)(ws + o);      o += ((size_t)(NN + 1) * 4 + 255) & ~(size_t)255;
  int*      bsum = (int*)(ws + o);      o += 256 * 4;
  unsigned* csrp = (unsigned*)(ws + o);

  k_zero   <<<SCAN_NB, 256, 0, stream>>>(cnt);
  k_cntprep<<<(NE + 255) / 256, 256, 0, stream>>>(ei, cnt, W, Wt);
  k_scan1  <<<SCAN_NB, 256, 0, stream>>>(cnt, off, dinv, bsum);
  k_scan2  <<<1, 256, 0, stream>>>(bsum, off);
  k_fill   <<<(NE + 255) / 256, 256, 0, stream>>>(ei, off, bsum, cnt, dinv, csrp);
  k_gemm   <<<(NN + 63) / 64, 256, 0, stream>>>(feats, Wt, xb);
  k_agg    <<<(NN + 3) / 4, 256, 0, stream>>>(xb, dinv, off, bsum, csrp, b, out);
}

// Round 11
// 152.618 us; speedup vs baseline: 1.1058x; 1.1058x over previous
//
#include <hip/hip_runtime.h>

#define NN 50000
#define NE 800000
#define KIN 512
#define HC 128
#define SCAN_NB ((NN + 255) / 256)   // 196

typedef float f32x4 __attribute__((ext_vector_type(4)));
typedef float f32x2 __attribute__((ext_vector_type(2)));
typedef short s16x8 __attribute__((ext_vector_type(8)));

__device__ __forceinline__ ushort f2bf(float f) {
  unsigned u = __float_as_uint(f);
  unsigned r = (u + 0x7FFFu + ((u >> 16) & 1u)) >> 16;  // RNE
  return (ushort)r;
}

// async global->LDS, 16B per lane, dest = wave-uniform base + lane*16
__device__ __forceinline__ void gload_lds16(const void* g, void* l) {
  __builtin_amdgcn_global_load_lds((const __attribute__((address_space(1))) void*)g,
                                   (__attribute__((address_space(3))) void*)l, 16, 0, 0);
}

// JAX threefry2x32-20, partitionable path: ctr=(0,i), key=(0,42), bits=o0^o1
__device__ __forceinline__ unsigned tf_bits(unsigned i) {
  unsigned x0 = 0u, x1 = i;
  const unsigned ks0 = 0u, ks1 = 42u, ks2 = 0x1BD11BDAu ^ 42u;
  x0 += ks0; x1 += ks1;
#define R(r) { x0 += x1; x1 = (x1 << r) | (x1 >> (32 - r)); x1 ^= x0; }
  R(13) R(15) R(26) R(6)
  x0 += ks1; x1 += ks2 + 1u;
  R(17) R(29) R(16) R(24)
  x0 += ks2; x1 += ks0 + 2u;
  R(13) R(15) R(26) R(6)
  x0 += ks0; x1 += ks1 + 3u;
  R(17) R(29) R(16) R(24)
  x0 += ks1; x1 += ks2 + 4u;
  R(13) R(15) R(26) R(6)
  x0 += ks2; x1 += ks0 + 5u;
#undef R
  return x0 ^ x1;
}

__global__ void k_zero(int* __restrict__ cnt) {
  int i = blockIdx.x * 256 + threadIdx.x;
  if (i < NN) cnt[i] = 0;
}

// count dst degrees (cnt zeroed by k_zero) + W transpose/convert
__global__ void k_cntprep(const int* __restrict__ ei, int* __restrict__ cnt,
                          const float* __restrict__ W, ushort* __restrict__ Wt) {
  int t = blockIdx.x * 256 + threadIdx.x;
  if (t < KIN * HC) {
    int c = t & (HC - 1), k = t >> 7;       // W row-major [k][c]
    Wt[c * KIN + k] = f2bf(W[t]);
  }
  if (t < NE) atomicAdd(&cnt[ei[NE + t]], 1);
}

// per-block exclusive scan of cnt; off = block-local exclusive, bsum[b] = total
__global__ void k_scan1(const int* __restrict__ cnt, int* __restrict__ off,
                        float* __restrict__ dinv, int* __restrict__ bsum) {
  const int i = blockIdx.x * 256 + threadIdx.x;
  const int lane = threadIdx.x & 63, wid = threadIdx.x >> 6;
  int c = (i < NN) ? cnt[i] : 0;
  if (i < NN) dinv[i] = rsqrtf((float)(c + 1));
  int v = c;
#pragma unroll
  for (int d = 1; d < 64; d <<= 1) {
    int t = __shfl_up(v, d);
    if (lane >= d) v += t;
  }
  __shared__ int wsum[4];
  if (lane == 63) wsum[wid] = v;
  __syncthreads();
  int wadd = 0;
#pragma unroll
  for (int w = 0; w < 3; w++) if (w < wid) wadd += wsum[w];
  int incl = v + wadd;
  if (i < NN) off[i] = incl - c;            // block-local exclusive
  if (threadIdx.x == 255) bsum[blockIdx.x] = incl;
}

// exclusive scan of SCAN_NB (<=256) block sums, in place; also off[NN]=NE
__global__ void k_scan2(int* __restrict__ bsum, int* __restrict__ off) {
  const int t = threadIdx.x;
  const int lane = t & 63, wid = t >> 6;
  int c = (t < SCAN_NB) ? bsum[t] : 0;
  int v = c;
#pragma unroll
  for (int d = 1; d < 64; d <<= 1) {
    int u = __shfl_up(v, d);
    if (lane >= d) v += u;
  }
  __shared__ int wsum[4];
  if (lane == 63) wsum[wid] = v;
  __syncthreads();
  int wadd = 0;
#pragma unroll
  for (int w = 0; w < 3; w++) if (w < wid) wadd += wsum[w];
  if (t < SCAN_NB) bsum[t] = v + wadd - c;  // exclusive
  if (t == 0) off[NN] = NE;
}

// csrp[off[d]+bsum[d>>8]+slot] = (bf16(dinv[src])<<16) | src   (src < 65536)
__global__ void k_fill(const int* __restrict__ ei, const int* __restrict__ off,
                       const int* __restrict__ bsum, int* __restrict__ cnt,
                       const float* __restrict__ dinv, unsigned* __restrict__ csrp) {
  int e = blockIdx.x * 256 + threadIdx.x;
  if (e >= NE) return;
  int s = ei[e], d = ei[NE + e];
  int slot = atomicAdd(&cnt[d], -1) - 1;    // cnt ends back at 0
  csrp[off[d] + bsum[d >> 8] + slot] = ((unsigned)f2bf(dinv[s]) << 16) | (unsigned)s;
}

// x = feats @ W  (bf16 MFMA, f32 acc, bf16 out). m97-style: 64x128 tile,
// 4 waves 2x2, single-buffer LDS staged via global_load_lds width=16.
// LDS reads XOR-chunk-swizzled (linear dest + pre-swizzled global source).
// [R10 single-barrier/B-from-global variant REGRESSED 27->58us: B global loads
//  (16 cachelines/frag) on the MFMA critical path + occupancy 4->3. Reverted.]
__launch_bounds__(256, 4)
__global__ void k_gemm(const float* __restrict__ feats, const ushort* __restrict__ Wt,
                       ushort* __restrict__ xb) {
  __shared__ __align__(16) float  As[64 * 64];    // 16 KB, 256 B/row (16 chunks)
  __shared__ __align__(16) ushort Bs[128 * 64];   // 16 KB, 128 B/row (8 chunks)
  const int tid = threadIdx.x;
  const int lane = tid & 63;
  const int w = tid >> 6;
  const int wm = w >> 1, wn = w & 1;
  const int rbase = blockIdx.x * 64;              // 782 blocks

  f32x4 acc[2][4];
#pragma unroll
  for (int mt = 0; mt < 2; mt++)
#pragma unroll
    for (int nt = 0; nt < 4; nt++) acc[mt][nt] = f32x4{0.f, 0.f, 0.f, 0.f};

  const int a_rt = w * 16 + (lane >> 4);          // + i*4 ; A tile row (lane's own)
  int a_gr[4];
#pragma unroll
  for (int i = 0; i < 4; i++) {
    int gr = rbase + a_rt + i * 4;
    a_gr[i] = (gr < NN) ? gr : NN - 1;
  }
  const int b_ct = w * 32 + (lane >> 3);              // + i*8 ; B tile col (Wt row)
  const int b_ch = ((lane & 7) ^ (b_ct & 7)) << 3;    // bf16 offset of swizzled chunk

  for (int ks = 0; ks < KIN; ks += 64) {
    __syncthreads();                               // prev-step LDS reads done
#pragma unroll
    for (int i = 0; i < 4; i++) {
      // A dest row ar = a_rt + i*4 -> (ar&7) = (a_rt&7) ^ ((i&1)<<2)
      int a_ch = ((lane & 15) ^ (a_rt & 7) ^ ((i & 1) << 2)) << 2;   // f32 offset
      gload_lds16(feats + (size_t)a_gr[i] * KIN + ks + a_ch,
                  (char*)As + (w * 16 + i * 4) * 256);
      gload_lds16(Wt + (size_t)(b_ct + i * 8) * KIN + ks + b_ch,
                  (char*)Bs + (w * 32 + i * 8) * 128);
    }
    __syncthreads();                               // staged (vmcnt drained by barrier)
#pragma unroll
    for (int kk = 0; kk < 2; kk++) {
      s16x8 bfr[4];
#pragma unroll
      for (int nt = 0; nt < 4; nt++) {
        int c = wn * 64 + nt * 16 + (lane & 15);
        int ch = (kk * 4 + (lane >> 4)) ^ (c & 7);
        bfr[nt] = *(const s16x8*)((const char*)Bs + c * 128 + ch * 16);
      }
#pragma unroll
      for (int mt = 0; mt < 2; mt++) {
        int r = wm * 32 + mt * 16 + (lane & 15);
        int c0 = kk * 8 + (lane >> 4) * 2;
        f32x4 f0 = *(const f32x4*)((const char*)As + r * 256 + ((c0 ^ (r & 7)) * 16));
        f32x4 f1 = *(const f32x4*)((const char*)As + r * 256 + (((c0 + 1) ^ (r & 7)) * 16));
        s16x8 af;
#pragma unroll
        for (int t = 0; t < 4; t++) {
          af[t]     = (short)f2bf(f0[t]);
          af[t + 4] = (short)f2bf(f1[t]);
        }
#pragma unroll
        for (int nt = 0; nt < 4; nt++)
          acc[mt][nt] = __builtin_amdgcn_mfma_f32_16x16x32_bf16(af, bfr[nt], acc[mt][nt], 0, 0, 0);
      }
    }
  }
  // C/D frag: col = lane&15, row = (lane>>4)*4 + j
#pragma unroll
  for (int mt = 0; mt < 2; mt++) {
    int rb = rbase + wm * 32 + mt * 16 + (lane >> 4) * 4;
#pragma unroll
    for (int nt = 0; nt < 4; nt++) {
      int c = wn * 64 + nt * 16 + (lane & 15);
#pragma unroll
      for (int j = 0; j < 4; j++) {
        int r = rb + j;
        if (r < NN) xb[(size_t)r * HC + c] = f2bf(acc[mt][nt][j]);
      }
    }
  }
}

// one wave per node, 4-way edge split: 16-lane group grp handles edges 4j+grp;
// each lane covers 8 channels (16B gather). Two shfl_xor levels to reduce.
__global__ void k_agg(const ushort* __restrict__ xb, const float* __restrict__ dinv,
                      const int* __restrict__ off, const int* __restrict__ bsum,
                      const unsigned* __restrict__ csrp,
                      const float* __restrict__ b, float* __restrict__ out) {
  int n = blockIdx.x * 4 + (threadIdx.x >> 6);
  if (n >= NN) return;
  const int lane = threadIdx.x & 63;
  const int grp = lane >> 4;          // edge slot parity (0..3)
  const int q = lane & 15;            // channels q*8 .. q*8+7
  const int beg = off[n] + bsum[n >> 8];
  const int end = off[n + 1] + ((n + 1 < NN) ? bsum[(n + 1) >> 8] : 0);
  const int deg = end - beg;
  const float dn = dinv[n];

  float a0, a1, a2, a3, a4, a5, a6, a7;
  {
    uint4 sv = *(const uint4*)(xb + (size_t)n * HC + q * 8);
    f32x4 b0 = *(const f32x4*)(b + q * 8);
    f32x4 b1 = *(const f32x4*)(b + q * 8 + 4);
    float sc = (grp == 0) ? dn * dn : 0.0f;   // self+bias only in group 0
    float z = (grp == 0) ? 1.0f : 0.0f;
    a0 = __uint_as_float(sv.x << 16)         * sc + b0[0] * z;
    a1 = __uint_as_float(sv.x & 0xFFFF0000u) * sc + b0[1] * z;
    a2 = __uint_as_float(sv.y << 16)         * sc + b0[2] * z;
    a3 = __uint_as_float(sv.y & 0xFFFF0000u) * sc + b0[3] * z;
    a4 = __uint_as_float(sv.z << 16)         * sc + b1[0] * z;
    a5 = __uint_as_float(sv.z & 0xFFFF0000u) * sc + b1[1] * z;
    a6 = __uint_as_float(sv.w << 16)         * sc + b1[2] * z;
    a7 = __uint_as_float(sv.w & 0xFFFF0000u) * sc + b1[3] * z;
  }

  const unsigned* cp = csrp + beg;
  const int np = (deg + 3) >> 2;      // quads
  unsigned uc = 0u;
  if (grp < deg) uc = cp[grp];        // edge 0*4+grp
  uint4 g = *(const uint4*)(xb + (size_t)(uc & 0xFFFFu) * HC + q * 8);
  for (int j = 0; j < np; ++j) {
    int idx = 4 * j + 4 + grp;        // next quad's edge for this group
    unsigned ucn = 0u;
    if (idx < deg) ucn = cp[idx];
    uint4 gn = *(const uint4*)(xb + (size_t)(ucn & 0xFFFFu) * HC + q * 8);
    float nr = __uint_as_float(uc & 0xFFFF0000u) * dn;  // bf16(dinv[src])*dinv[n]
    a0 += __uint_as_float(g.x << 16)         * nr;
    a1 += __uint_as_float(g.x & 0xFFFF0000u) * nr;
    a2 += __uint_as_float(g.y << 16)         * nr;
    a3 += __uint_as_float(g.y & 0xFFFF0000u) * nr;
    a4 += __uint_as_float(g.z << 16)         * nr;
    a5 += __uint_as_float(g.z & 0xFFFF0000u) * nr;
    a6 += __uint_as_float(g.w << 16)         * nr;
    a7 += __uint_as_float(g.w & 0xFFFF0000u) * nr;
    uc = ucn; g = gn;
  }
  // reduce across the 4 groups
#define RED(A) A += __shfl_xor(A, 16); A += __shfl_xor(A, 32);
  RED(a0) RED(a1) RED(a2) RED(a3) RED(a4) RED(a5) RED(a6) RED(a7)
#undef RED
  // group grp finalizes channels q*8+2*grp, q*8+2*grp+1
  float vx = (grp == 0) ? a0 : (grp == 1) ? a2 : (grp == 2) ? a4 : a6;
  float vy = (grp == 0) ? a1 : (grp == 1) ? a3 : (grp == 2) ? a5 : a7;
  vx = fmaxf(vx, 0.f) * 2.f;
  vy = fmaxf(vy, 0.f) * 2.f;
  int i0 = n * HC + q * 8 + 2 * grp;
  f32x2 r;
  r.x = (tf_bits((unsigned)i0)     >> 31) ? 0.f : vx;
  r.y = (tf_bits((unsigned)i0 + 1) >> 31) ? 0.f : vy;
  *(f32x2*)(out + i0) = r;
}

extern "C" void kernel_launch(void* const* d_in, const int* in_sizes, int n_in,
                              void* d_out, int out_size, void* d_ws, size_t ws_size,
                              hipStream_t stream) {
  const float* feats = (const float*)d_in[0];
  const float* W     = (const float*)d_in[1];
  const float* b     = (const float*)d_in[2];
  const int*   ei    = (const int*)d_in[3];
  float* out = (float*)d_out;

  // ws: xb[NN*HC] bf16 | Wt[HC*KIN] bf16 | dinv[NN] f32 | cnt[NN] i32 |
  //     off[NN+1] i32 | bsum[256] i32 | csrp[NE] u32   (~17 MB)
  char* ws = (char*)d_ws;
  size_t o = 0;
  ushort*   xb   = (ushort*)(ws + o);   o += ((size_t)NN * HC * 2 + 255) & ~(size_t)255;
  ushort*   Wt   = (ushort*)(ws + o);   o += ((size_t)HC * KIN * 2 + 255) & ~(size_t)255;
  float*    dinv = (float*)(ws + o);    o += ((size_t)NN * 4 + 255) & ~(size_t)255;
  int*      cnt  = (int*)(ws + o);      o += ((size_t)NN * 4 + 255) & ~(size_t)255;
  int*      off  = (int*)(ws + o);      o += ((size_t)(NN + 1) * 4 + 255) & ~(size_t)255;
  int*      bsum = (int*)(ws + o);      o += 256 * 4;
  unsigned* csrp = (unsigned*)(ws + o);

  k_zero   <<<SCAN_NB, 256, 0, stream>>>(cnt);
  k_cntprep<<<(NE + 255) / 256, 256, 0, stream>>>(ei, cnt, W, Wt);
  k_scan1  <<<SCAN_NB, 256, 0, stream>>>(cnt, off, dinv, bsum);
  k_scan2  <<<1, 256, 0, stream>>>(bsum, off);
  k_fill   <<<(NE + 255) / 256, 256, 0, stream>>>(ei, off, bsum, cnt, dinv, csrp);
  k_gemm   <<<(NN + 63) / 64, 256, 0, stream>>>(feats, Wt, xb);
  k_agg    <<<(NN + 3) / 4, 256, 0, stream>>>(xb, dinv, off, bsum, csrp, b, out);
}

// Round 12
// 150.462 us; speedup vs baseline: 1.1217x; 1.0143x over previous
//
#include <hip/hip_runtime.h>

#define NN 50000
#define NE 800000
#define KIN 512
#define HC 128
#define SCAN_NB ((NN + 255) / 256)   // 196

typedef float f32x4 __attribute__((ext_vector_type(4)));
typedef float f32x2 __attribute__((ext_vector_type(2)));
typedef short s16x8 __attribute__((ext_vector_type(8)));

__device__ __forceinline__ ushort f2bf(float f) {
  unsigned u = __float_as_uint(f);
  unsigned r = (u + 0x7FFFu + ((u >> 16) & 1u)) >> 16;  // RNE
  return (ushort)r;
}

// async global->LDS, 16B per lane, dest = wave-uniform base + lane*16
__device__ __forceinline__ void gload_lds16(const void* g, void* l) {
  __builtin_amdgcn_global_load_lds((const __attribute__((address_space(1))) void*)g,
                                   (__attribute__((address_space(3))) void*)l, 16, 0, 0);
}

// JAX threefry2x32-20, partitionable path: ctr=(0,i), key=(0,42), bits=o0^o1
__device__ __forceinline__ unsigned tf_bits(unsigned i) {
  unsigned x0 = 0u, x1 = i;
  const unsigned ks0 = 0u, ks1 = 42u, ks2 = 0x1BD11BDAu ^ 42u;
  x0 += ks0; x1 += ks1;
#define R(r) { x0 += x1; x1 = (x1 << r) | (x1 >> (32 - r)); x1 ^= x0; }
  R(13) R(15) R(26) R(6)
  x0 += ks1; x1 += ks2 + 1u;
  R(17) R(29) R(16) R(24)
  x0 += ks2; x1 += ks0 + 2u;
  R(13) R(15) R(26) R(6)
  x0 += ks0; x1 += ks1 + 3u;
  R(17) R(29) R(16) R(24)
  x0 += ks1; x1 += ks2 + 4u;
  R(13) R(15) R(26) R(6)
  x0 += ks2; x1 += ks0 + 5u;
#undef R
  return x0 ^ x1;
}

__global__ void k_zero(int* __restrict__ cnt) {
  int i = blockIdx.x * 256 + threadIdx.x;
  if (i < NN) cnt[i] = 0;
}

// count dst degrees (cnt zeroed by k_zero) + W transpose/convert
__global__ void k_cntprep(const int* __restrict__ ei, int* __restrict__ cnt,
                          const float* __restrict__ W, ushort* __restrict__ Wt) {
  int t = blockIdx.x * 256 + threadIdx.x;
  if (t < KIN * HC) {
    int c = t & (HC - 1), k = t >> 7;       // W row-major [k][c]
    Wt[c * KIN + k] = f2bf(W[t]);
  }
  if (t < NE) atomicAdd(&cnt[ei[NE + t]], 1);
}

// per-block exclusive scan of cnt; off = block-local exclusive, bsum[b] = total
__global__ void k_scan1(const int* __restrict__ cnt, int* __restrict__ off,
                        float* __restrict__ dinv, int* __restrict__ bsum) {
  const int i = blockIdx.x * 256 + threadIdx.x;
  const int lane = threadIdx.x & 63, wid = threadIdx.x >> 6;
  int c = (i < NN) ? cnt[i] : 0;
  if (i < NN) dinv[i] = rsqrtf((float)(c + 1));
  int v = c;
#pragma unroll
  for (int d = 1; d < 64; d <<= 1) {
    int t = __shfl_up(v, d);
    if (lane >= d) v += t;
  }
  __shared__ int wsum[4];
  if (lane == 63) wsum[wid] = v;
  __syncthreads();
  int wadd = 0;
#pragma unroll
  for (int w = 0; w < 3; w++) if (w < wid) wadd += wsum[w];
  int incl = v + wadd;
  if (i < NN) off[i] = incl - c;            // block-local exclusive
  if (threadIdx.x == 255) bsum[blockIdx.x] = incl;
}

// exclusive scan of SCAN_NB (<=256) block sums, in place; also off[NN]=NE
__global__ void k_scan2(int* __restrict__ bsum, int* __restrict__ off) {
  const int t = threadIdx.x;
  const int lane = t & 63, wid = t >> 6;
  int c = (t < SCAN_NB) ? bsum[t] : 0;
  int v = c;
#pragma unroll
  for (int d = 1; d < 64; d <<= 1) {
    int u = __shfl_up(v, d);
    if (lane >= d) v += u;
  }
  __shared__ int wsum[4];
  if (lane == 63) wsum[wid] = v;
  __syncthreads();
  int wadd = 0;
#pragma unroll
  for (int w = 0; w < 3; w++) if (w < wid) wadd += wsum[w];
  if (t < SCAN_NB) bsum[t] = v + wadd - c;  // exclusive
  if (t == 0) off[NN] = NE;
}

// csrp[off[d]+bsum[d>>8]+slot] = (bf16(dinv[src])<<16) | src   (src < 65536)
__global__ void k_fill(const int* __restrict__ ei, const int* __restrict__ off,
                       const int* __restrict__ bsum, int* __restrict__ cnt,
                       const float* __restrict__ dinv, unsigned* __restrict__ csrp) {
  int e = blockIdx.x * 256 + threadIdx.x;
  if (e >= NE) return;
  int s = ei[e], d = ei[NE + e];
  int slot = atomicAdd(&cnt[d], -1) - 1;    // cnt ends back at 0
  csrp[off[d] + bsum[d >> 8] + slot] = ((unsigned)f2bf(dinv[s]) << 16) | (unsigned)s;
}

// x = feats @ W  (bf16 MFMA, f32 acc, bf16 out). 32x128 tile, 4 waves 2x2
// (each 16 rows x 64 cols), single-buffer LDS via global_load_lds width=16,
// XOR-chunk swizzle (linear dest + pre-swizzled source). 1563 blocks, 24KB
// LDS -> ~6 blocks/CU: double the per-CU overlap of the 64-row version.
__launch_bounds__(256, 6)
__global__ void k_gemm(const float* __restrict__ feats, const ushort* __restrict__ Wt,
                       ushort* __restrict__ xb) {
  __shared__ __align__(16) float  As[32 * 64];    // 8 KB, 256 B/row (16 chunks)
  __shared__ __align__(16) ushort Bs[128 * 64];   // 16 KB, 128 B/row (8 chunks)
  const int tid = threadIdx.x;
  const int lane = tid & 63;
  const int w = tid >> 6;
  const int wm = w >> 1, wn = w & 1;
  const int rbase = blockIdx.x * 32;              // 1563 blocks

  f32x4 acc[4];
#pragma unroll
  for (int nt = 0; nt < 4; nt++) acc[nt] = f32x4{0.f, 0.f, 0.f, 0.f};

  // A staging: wave w stages rows w*8 + i*4 + (lane>>4), i=0..1
  const int a_rt = w * 8 + (lane >> 4);
  int a_gr[2];
#pragma unroll
  for (int i = 0; i < 2; i++) {
    int gr = rbase + a_rt + i * 4;
    a_gr[i] = (gr < NN) ? gr : NN - 1;
  }
  const int b_ct = w * 32 + (lane >> 3);              // + i*8 ; B tile col (Wt row)
  const int b_ch = ((lane & 7) ^ (b_ct & 7)) << 3;    // bf16 offset of swizzled chunk

  for (int ks = 0; ks < KIN; ks += 64) {
    __syncthreads();                               // prev-step LDS reads done
#pragma unroll
    for (int i = 0; i < 2; i++) {
      // A dest row ar = a_rt + i*4 -> (ar&7) = (a_rt&7) ^ ((i&1)<<2)
      int a_ch = ((lane & 15) ^ (a_rt & 7) ^ ((i & 1) << 2)) << 2;   // f32 offset
      gload_lds16(feats + (size_t)a_gr[i] * KIN + ks + a_ch,
                  (char*)As + (w * 8 + i * 4) * 256);
    }
#pragma unroll
    for (int i = 0; i < 4; i++)
      gload_lds16(Wt + (size_t)(b_ct + i * 8) * KIN + ks + b_ch,
                  (char*)Bs + (w * 32 + i * 8) * 128);
    __syncthreads();                               // staged (vmcnt drained by barrier)
#pragma unroll
    for (int kk = 0; kk < 2; kk++) {
      s16x8 bfr[4];
#pragma unroll
      for (int nt = 0; nt < 4; nt++) {
        int c = wn * 64 + nt * 16 + (lane & 15);
        int ch = (kk * 4 + (lane >> 4)) ^ (c & 7);
        bfr[nt] = *(const s16x8*)((const char*)Bs + c * 128 + ch * 16);
      }
      int r = wm * 16 + (lane & 15);
      int c0 = kk * 8 + (lane >> 4) * 2;
      f32x4 f0 = *(const f32x4*)((const char*)As + r * 256 + ((c0 ^ (r & 7)) * 16));
      f32x4 f1 = *(const f32x4*)((const char*)As + r * 256 + (((c0 + 1) ^ (r & 7)) * 16));
      s16x8 af;
#pragma unroll
      for (int t = 0; t < 4; t++) {
        af[t]     = (short)f2bf(f0[t]);
        af[t + 4] = (short)f2bf(f1[t]);
      }
#pragma unroll
      for (int nt = 0; nt < 4; nt++)
        acc[nt] = __builtin_amdgcn_mfma_f32_16x16x32_bf16(af, bfr[nt], acc[nt], 0, 0, 0);
    }
  }
  // C/D frag: col = lane&15, row = (lane>>4)*4 + j
  {
    int rb = rbase + wm * 16 + (lane >> 4) * 4;
#pragma unroll
    for (int nt = 0; nt < 4; nt++) {
      int c = wn * 64 + nt * 16 + (lane & 15);
#pragma unroll
      for (int j = 0; j < 4; j++) {
        int r = rb + j;
        if (r < NN) xb[(size_t)r * HC + c] = f2bf(acc[nt][j]);
      }
    }
  }
}

// one wave per node, 4-way edge split: 16-lane group grp handles edges 4j+grp;
// each lane covers 8 channels (16B gather). Two shfl_xor levels to reduce.
__global__ void k_agg(const ushort* __restrict__ xb, const float* __restrict__ dinv,
                      const int* __restrict__ off, const int* __restrict__ bsum,
                      const unsigned* __restrict__ csrp,
                      const float* __restrict__ b, float* __restrict__ out) {
  int n = blockIdx.x * 4 + (threadIdx.x >> 6);
  if (n >= NN) return;
  const int lane = threadIdx.x & 63;
  const int grp = lane >> 4;          // edge slot parity (0..3)
  const int q = lane & 15;            // channels q*8 .. q*8+7
  const int beg = off[n] + bsum[n >> 8];
  const int end = off[n + 1] + ((n + 1 < NN) ? bsum[(n + 1) >> 8] : 0);
  const int deg = end - beg;
  const float dn = dinv[n];

  float a0, a1, a2, a3, a4, a5, a6, a7;
  {
    uint4 sv = *(const uint4*)(xb + (size_t)n * HC + q * 8);
    f32x4 b0 = *(const f32x4*)(b + q * 8);
    f32x4 b1 = *(const f32x4*)(b + q * 8 + 4);
    float sc = (grp == 0) ? dn * dn : 0.0f;   // self+bias only in group 0
    float z = (grp == 0) ? 1.0f : 0.0f;
    a0 = __uint_as_float(sv.x << 16)         * sc + b0[0] * z;
    a1 = __uint_as_float(sv.x & 0xFFFF0000u) * sc + b0[1] * z;
    a2 = __uint_as_float(sv.y << 16)         * sc + b0[2] * z;
    a3 = __uint_as_float(sv.y & 0xFFFF0000u) * sc + b0[3] * z;
    a4 = __uint_as_float(sv.z << 16)         * sc + b1[0] * z;
    a5 = __uint_as_float(sv.z & 0xFFFF0000u) * sc + b1[1] * z;
    a6 = __uint_as_float(sv.w << 16)         * sc + b1[2] * z;
    a7 = __uint_as_float(sv.w & 0xFFFF0000u) * sc + b1[3] * z;
  }

  const unsigned* cp = csrp + beg;
  const int np = (deg + 3) >> 2;      // quads
  unsigned uc = 0u;
  if (grp < deg) uc = cp[grp];        // edge 0*4+grp
  uint4 g = *(const uint4*)(xb + (size_t)(uc & 0xFFFFu) * HC + q * 8);
  for (int j = 0; j < np; ++j) {
    int idx = 4 * j + 4 + grp;        // next quad's edge for this group
    unsigned ucn = 0u;
    if (idx < deg) ucn = cp[idx];
    uint4 gn = *(const uint4*)(xb + (size_t)(ucn & 0xFFFFu) * HC + q * 8);
    float nr = __uint_as_float(uc & 0xFFFF0000u) * dn;  // bf16(dinv[src])*dinv[n]
    a0 += __uint_as_float(g.x << 16)         * nr;
    a1 += __uint_as_float(g.x & 0xFFFF0000u) * nr;
    a2 += __uint_as_float(g.y << 16)         * nr;
    a3 += __uint_as_float(g.y & 0xFFFF0000u) * nr;
    a4 += __uint_as_float(g.z << 16)         * nr;
    a5 += __uint_as_float(g.z & 0xFFFF0000u) * nr;
    a6 += __uint_as_float(g.w << 16)         * nr;
    a7 += __uint_as_float(g.w & 0xFFFF0000u) * nr;
    uc = ucn; g = gn;
  }
  // reduce across the 4 groups
#define RED(A) A += __shfl_xor(A, 16); A += __shfl_xor(A, 32);
  RED(a0) RED(a1) RED(a2) RED(a3) RED(a4) RED(a5) RED(a6) RED(a7)
#undef RED
  // group grp finalizes channels q*8+2*grp, q*8+2*grp+1
  float vx = (grp == 0) ? a0 : (grp == 1) ? a2 : (grp == 2) ? a4 : a6;
  float vy = (grp == 0) ? a1 : (grp == 1) ? a3 : (grp == 2) ? a5 : a7;
  vx = fmaxf(vx, 0.f) * 2.f;
  vy = fmaxf(vy, 0.f) * 2.f;
  int i0 = n * HC + q * 8 + 2 * grp;
  f32x2 r;
  r.x = (tf_bits((unsigned)i0)     >> 31) ? 0.f : vx;
  r.y = (tf_bits((unsigned)i0 + 1) >> 31) ? 0.f : vy;
  *(f32x2*)(out + i0) = r;
}

extern "C" void kernel_launch(void* const* d_in, const int* in_sizes, int n_in,
                              void* d_out, int out_size, void* d_ws, size_t ws_size,
                              hipStream_t stream) {
  const float* feats = (const float*)d_in[0];
  const float* W     = (const float*)d_in[1];
  const float* b     = (const float*)d_in[2];
  const int*   ei    = (const int*)d_in[3];
  float* out = (float*)d_out;

  // ws: xb[NN*HC] bf16 | Wt[HC*KIN] bf16 | dinv[NN] f32 | cnt[NN] i32 |
  //     off[NN+1] i32 | bsum[256] i32 | csrp[NE] u32   (~17 MB)
  char* ws = (char*)d_ws;
  size_t o = 0;
  ushort*   xb   = (ushort*)(ws + o);   o += ((size_t)NN * HC * 2 + 255) & ~(size_t)255;
  ushort*   Wt   = (ushort*)(ws + o);   o += ((size_t)HC * KIN * 2 + 255) & ~(size_t)255;
  float*    dinv = (float*)(ws + o);    o += ((size_t)NN * 4 + 255) & ~(size_t)255;
  int*      cnt  = (int*)(ws + o);      o += ((size_t)NN * 4 + 255) & ~(size_t)255;
  int*      off  = (int*)(ws + o);      o += ((size_t)(NN + 1) * 4 + 255) & ~(size_t)255;
  int*      bsum = (int*)(ws + o);      o += 256 * 4;
  unsigned* csrp = (unsigned*)(ws + o);

  k_zero   <<<SCAN_NB, 256, 0, stream>>>(cnt);
  k_cntprep<<<(NE + 255) / 256, 256, 0, stream>>>(ei, cnt, W, Wt);
  k_scan1  <<<SCAN_NB, 256, 0, stream>>>(cnt, off, dinv, bsum);
  k_scan2  <<<1, 256, 0, stream>>>(bsum, off);
  k_fill   <<<(NE + 255) / 256, 256, 0, stream>>>(ei, off, bsum, cnt, dinv, csrp);
  k_gemm   <<<(NN + 31) / 32, 256, 0, stream>>>(feats, Wt, xb);
  k_agg    <<<(NN + 3) / 4, 256, 0, stream>>>(xb, dinv, off, bsum, csrp, b, out);
}